// Round 3
// baseline (731.191 us; speedup 1.0000x reference)
//
#include <hip/hip_runtime.h>
#include <hip/hip_bf16.h>
#include <math.h>

// ---------------------------------------------------------------------------
// RPN fused kernel for MI355X (gfx950)
//   trunk : 3x3 conv 64->512 + bias + relu   (bf16x2 split MFMA, 3 passes)
//   heads : 1x1 conv 512->9 (sigmoid) and 512->36 (linear), deltas masked by
//           score > 0.7, output [B,H,W,45] fp32
// Round 3: occupancy push. Wave tile 64pos x 128ch -> 32pos x 128ch:
//   acc 128 -> 64 AGPRs, arena 48 KB -> 29 KB, launch_bounds(256,3).
//   8192 wgs (1 h-row x 32 w x 512 ch each). Weight stream/prefetch identical
//   to round 2 (depth-4 rotating register prefetch, lane-order btI layout).
// ---------------------------------------------------------------------------

typedef __bf16 bf16x8 __attribute__((ext_vector_type(8)));
typedef __bf16 bf16x4 __attribute__((ext_vector_type(4)));
typedef float  f32x4  __attribute__((ext_vector_type(4)));

#define SI_STEPS  144                   // 18 k-chunks x 8 n-subtiles
#define SI_SLOTS  148                   // +4 pad slots for prefetch overrun
#define BTI_ELEMS (SI_SLOTS * 256 * 16) // interleaved trunk weights (bf16)
#define BT2_ELEMS (48 * 512)            // head weights, [o][k] k-major

// ---------------------------------------------------------------------------
// prep: split fp32 weights into bf16 hi/lo
//   trunk  -> btI[si][tid][hi8|lo8]  (exact per-lane load order of rpn_main)
//   heads  -> bt2_hi/bt2_lo [o][k]
// ---------------------------------------------------------------------------
__global__ __launch_bounds__(256) void rpn_prep(
    const float* __restrict__ wb,   // [3][3][64][512]
    const float* __restrict__ wc,   // [512][9]
    const float* __restrict__ wr,   // [512][36]
    __bf16* __restrict__ btI,
    __bf16* __restrict__ bt2_hi, __bf16* __restrict__ bt2_lo)
{
    int t = blockIdx.x * 256 + threadIdx.x;
    if (t < SI_STEPS * 256 * 8) {
        int j    = t & 7;
        int lane = (t >> 3) & 63;
        int wv   = (t >> 9) & 3;
        int si   = t >> 11;              // 0..143
        int s    = si >> 3;              // k-chunk 0..17
        int l    = si & 7;               // n-subtile 0..7
        int lr   = lane & 15;
        int q    = lane >> 4;
        int n    = wv * 128 + l * 16 + lr;
        int kg   = s * 32 + q * 8 + j;   // 0..575
        int tap  = kg >> 6, c = kg & 63; // k = (ky*3+kx)*64 + c
        float v  = wb[(tap * 64 + c) * 512 + n];
        __bf16 h = (__bf16)v;
        int base = (si * 256 + wv * 64 + lane) * 16;
        btI[base + j]     = h;
        btI[base + 8 + j] = (__bf16)(v - (float)h);
    } else if (t < SI_STEPS * 256 * 8 + BT2_ELEMS) {
        int jj = t - SI_STEPS * 256 * 8;
        int k = jj & 511;
        int o = jj >> 9;                 // 0..47
        float v = 0.f;
        if (o < 9)       v = wc[k * 9 + o];
        else if (o < 45) v = wr[k * 36 + (o - 9)];
        __bf16 h = (__bf16)v;
        bt2_hi[jj] = h;
        bt2_lo[jj] = (__bf16)(v - (float)h);
    }
}

// ---------------------------------------------------------------------------
// main fused kernel: 8192 workgroups x 256 threads
//   tile = 32 output positions (1 h-row x 32 w) x 512 channels
//   wave w owns channel slice [128w, 128w+128); per wave acc[2][8] = 64 AGPR
// LDS arena (29376 B), phase-overlapped:
//   phase1: xs_hi [3][34][72] bf16 @0 (14688 B), xs_lo @14688 (14688 B)
//   phase2: zbuf  float[32][48] @0 (6144 B),
//           fbuf per wave @6144 + w*4608: fh [32][36] bf16, fl +2304 B
// ---------------------------------------------------------------------------
#define XS_LO_OFF   14688
#define FB_OFF      6144
#define FB_PER_WAVE 4608
#define ARENA_BYTES 29376

__global__ __launch_bounds__(256, 3) void rpn_main(
    const float* __restrict__ x,        // [4][256][256][64]
    const float* __restrict__ b_base,   // [512]
    const float* __restrict__ b_cls,    // [9]
    const float* __restrict__ b_reg,    // [36]
    const __bf16* __restrict__ btI,
    const __bf16* __restrict__ bt2_hi, const __bf16* __restrict__ bt2_lo,
    float* __restrict__ out)            // [4][256][256][45]
{
    __shared__ char smem[ARENA_BYTES];
    __bf16* xs_hi = (__bf16*)smem;
    __bf16* xs_lo = (__bf16*)(smem + XS_LO_OFF);
    float*  zbuf  = (float*)smem;

    const int tid  = threadIdx.x;
    const int wave = tid >> 6;
    const int lane = tid & 63;
    const int q    = lane >> 4;     // 0..3
    const int lr   = lane & 15;     // 0..15
    const int n0   = wave * 128;    // wave's channel-slice base

    const int wg  = blockIdx.x;
    const int b   = wg >> 11;           // 2048 tiles per image
    const int rem = wg & 2047;
    const int h0  = rem >> 3;           // single h-row per tile
    const int w0  = (rem & 7) * 32;     // 32 w-positions per tile

    // ---- stage x patch (3 rows x 34 pos x 64 ch) as bf16 hi/lo ----
    for (int i = 0; i < 7; ++i) {
        int flat = tid + i * 256;
        if (flat < 3 * 34 * 16) {
            int cq  = flat & 15;          // channel quad
            int rp  = flat >> 4;          // 0..101
            int row = rp / 34;
            int pos = rp - row * 34;
            int hh  = h0 - 1 + row;
            int ww  = w0 - 1 + pos;
            bf16x4 h4, l4;
            if (hh >= 0 && hh < 256 && ww >= 0 && ww < 256) {
                const float4 v = *(const float4*)&x[(((b * 256 + hh) * 256 + ww) * 64 + cq * 4)];
                float vs[4] = {v.x, v.y, v.z, v.w};
                #pragma unroll
                for (int j = 0; j < 4; ++j) {
                    __bf16 h = (__bf16)vs[j];
                    h4[j] = h;
                    l4[j] = (__bf16)(vs[j] - (float)h);
                }
            } else {
                #pragma unroll
                for (int j = 0; j < 4; ++j) { h4[j] = (__bf16)0.f; l4[j] = (__bf16)0.f; }
            }
            int off = (row * 34 + pos) * 72 + cq * 4;
            *(bf16x4*)&xs_hi[off] = h4;
            *(bf16x4*)&xs_lo[off] = l4;
        }
    }
    __syncthreads();   // barrier 1: xs ready

    // ---- trunk K-loop: 144 si-steps, barrier-free, depth-4 weight prefetch ----
    f32x4 acc[2][8];
    #pragma unroll
    for (int km = 0; km < 2; ++km)
        #pragma unroll
        for (int l = 0; l < 8; ++l)
            acc[km][l] = (f32x4){0.f, 0.f, 0.f, 0.f};

    // per-lane weight stream base: 32 B per si-step (hi8 then lo8)
    const __bf16* bq = btI + (size_t)tid * 16;

    bf16x8 pfh[4], pfl[4];
    #pragma unroll
    for (int p = 0; p < 4; ++p) {
        const __bf16* ptr = bq + (size_t)p * 4096;
        pfh[p] = *(const bf16x8*)ptr;
        pfl[p] = *(const bf16x8*)(ptr + 8);
    }

    for (int s = 0; s < 18; ++s) {
        const int tap = s >> 1;
        const int ky  = tap / 3;
        const int kx  = tap - ky * 3;
        const int c0  = (s & 1) * 32 + q * 8;
        bf16x8 ah[2], al[2];
        #pragma unroll
        for (int km = 0; km < 2; ++km) {
            int pos  = (km << 4) + lr + kx;
            int off  = (ky * 34 + pos) * 72 + c0;
            ah[km] = *(const bf16x8*)&xs_hi[off];
            al[km] = *(const bf16x8*)&xs_lo[off];
        }
        #pragma unroll
        for (int l = 0; l < 8; ++l) {
            const int slot = l & 3;            // (s*8+l) & 3 == l & 3
            bf16x8 bh = pfh[slot], bl = pfl[slot];
            // issue refill for si+4 into the slot just consumed
            {
                int nsi = s * 8 + l + 4;       // <= 147, pad slots allocated
                const __bf16* ptr = bq + (size_t)nsi * 4096;
                pfh[slot] = *(const bf16x8*)ptr;
                pfl[slot] = *(const bf16x8*)(ptr + 8);
            }
            #pragma unroll
            for (int km = 0; km < 2; ++km)
                acc[km][l] = __builtin_amdgcn_mfma_f32_16x16x32_bf16(ah[km], bh, acc[km][l], 0, 0, 0);
            #pragma unroll
            for (int km = 0; km < 2; ++km)
                acc[km][l] = __builtin_amdgcn_mfma_f32_16x16x32_bf16(ah[km], bl, acc[km][l], 0, 0, 0);
            #pragma unroll
            for (int km = 0; km < 2; ++km)
                acc[km][l] = __builtin_amdgcn_mfma_f32_16x16x32_bf16(al[km], bh, acc[km][l], 0, 0, 0);
        }
    }

    __syncthreads();   // barrier 2: xs dead, safe to reuse arena

    // zero the z accumulation buffer
    for (int i = tid; i < 32 * 48; i += 256) zbuf[i] = 0.f;
    __syncthreads();   // barrier 3: zbuf zeroed

    // ---- fused 1x1 heads: per-wave k-slice GEMM feat[32][128] x w2[128][48] ----
    __bf16* fh = (__bf16*)(smem + FB_OFF + wave * FB_PER_WAVE);
    __bf16* fl = fh + 32 * 36;

    f32x4 acc2[2][3];
    #pragma unroll
    for (int km = 0; km < 2; ++km)
        #pragma unroll
        for (int ns = 0; ns < 3; ++ns)
            acc2[km][ns] = (f32x4){0.f, 0.f, 0.f, 0.f};

    for (int sub = 0; sub < 4; ++sub) {       // 4 k-chunks of 32 within the slice
        // dump this wave's 32-channel slice of feat (bias+relu, bf16 hi/lo)
        #pragma unroll
        for (int lh = 0; lh < 2; ++lh) {
            int l = sub * 2 + lh;
            float bias = b_base[n0 + l * 16 + lr];
            #pragma unroll
            for (int km = 0; km < 2; ++km) {
                #pragma unroll
                for (int r = 0; r < 4; ++r) {
                    float v = acc[km][l][r] + bias;
                    v = v > 0.f ? v : 0.f;
                    __bf16 h = (__bf16)v;
                    int row = km * 16 + q * 4 + r;
                    int col = lh * 16 + lr;
                    fh[row * 36 + col] = h;
                    fl[row * 36 + col] = (__bf16)(v - (float)h);
                }
            }
        }
        asm volatile("s_waitcnt lgkmcnt(0)" ::: "memory");  // wave-local RAW fence

        // A-frags: feat rows, k-local = q*8..q*8+7 (8-byte aligned -> 2x b64)
        bf16x8 fah[2], fal[2];
        #pragma unroll
        for (int km = 0; km < 2; ++km) {
            int off = (km * 16 + lr) * 36 + q * 8;
            union { bf16x8 v8; bf16x4 v4[2]; } uh, ul;
            uh.v4[0] = *(const bf16x4*)&fh[off];
            uh.v4[1] = *(const bf16x4*)&fh[off + 4];
            ul.v4[0] = *(const bf16x4*)&fl[off];
            ul.v4[1] = *(const bf16x4*)&fl[off + 4];
            fah[km] = uh.v8;
            fal[km] = ul.v8;
        }

        const int kg = n0 + sub * 32 + q * 8;   // global k for B frags
        // ns = 0 (contains the 9 score cols): 3-pass hi/lo
        {
            int eo = (0 * 16 + lr) * 512 + kg;
            bf16x8 wh = *(const bf16x8*)&bt2_hi[eo];
            bf16x8 wl = *(const bf16x8*)&bt2_lo[eo];
            #pragma unroll
            for (int km = 0; km < 2; ++km)
                acc2[km][0] = __builtin_amdgcn_mfma_f32_16x16x32_bf16(fah[km], wh, acc2[km][0], 0, 0, 0);
            #pragma unroll
            for (int km = 0; km < 2; ++km)
                acc2[km][0] = __builtin_amdgcn_mfma_f32_16x16x32_bf16(fah[km], wl, acc2[km][0], 0, 0, 0);
            #pragma unroll
            for (int km = 0; km < 2; ++km)
                acc2[km][0] = __builtin_amdgcn_mfma_f32_16x16x32_bf16(fal[km], wh, acc2[km][0], 0, 0, 0);
        }
        // ns = 1,2 (pure delta cols): single pass
        #pragma unroll
        for (int ns = 1; ns < 3; ++ns) {
            int eo = (ns * 16 + lr) * 512 + kg;
            bf16x8 wh = *(const bf16x8*)&bt2_hi[eo];
            #pragma unroll
            for (int km = 0; km < 2; ++km)
                acc2[km][ns] = __builtin_amdgcn_mfma_f32_16x16x32_bf16(fah[km], wh, acc2[km][ns], 0, 0, 0);
        }
    }

    // k-slice reduction across waves
    #pragma unroll
    for (int km = 0; km < 2; ++km)
        #pragma unroll
        for (int ns = 0; ns < 3; ++ns)
            #pragma unroll
            for (int r = 0; r < 4; ++r) {
                int row = km * 16 + q * 4 + r;
                int col = ns * 16 + lr;
                atomicAdd(&zbuf[row * 48 + col], acc2[km][ns][r]);
            }
    __syncthreads();   // barrier 4: z complete

    // ---- epilogue: sigmoid, threshold mask, store ----
    for (int i = tid; i < 32 * 45; i += 256) {
        int m = i / 45;
        int o = i - m * 45;
        float z = zbuf[m * 48 + o];
        float v;
        if (o < 9) {
            v = 1.f / (1.f + expf(-(z + b_cls[o])));
        } else {
            int d = o - 9;
            int a = d >> 2;
            float s = 1.f / (1.f + expf(-(zbuf[m * 48 + a] + b_cls[a])));
            v = (s > 0.7f) ? (z + b_reg[d]) : 0.f;
        }
        out[(((b * 256 + h0) * 256) + w0 + m) * 45 + o] = v;
    }
}

// ---------------------------------------------------------------------------
extern "C" void kernel_launch(void* const* d_in, const int* in_sizes, int n_in,
                              void* d_out, int out_size, void* d_ws, size_t ws_size,
                              hipStream_t stream)
{
    const float* x      = (const float*)d_in[0];
    const float* w_base = (const float*)d_in[1];
    const float* b_base = (const float*)d_in[2];
    const float* w_cls  = (const float*)d_in[3];
    const float* b_cls  = (const float*)d_in[4];
    const float* w_reg  = (const float*)d_in[5];
    const float* b_reg  = (const float*)d_in[6];
    float* out = (float*)d_out;

    __bf16* btI    = (__bf16*)d_ws;
    __bf16* bt2_hi = btI + BTI_ELEMS;
    __bf16* bt2_lo = bt2_hi + BT2_ELEMS;

    rpn_prep<<<(SI_STEPS * 256 * 8 + BT2_ELEMS + 255) / 256, 256, 0, stream>>>(
        w_base, w_cls, w_reg, btI, bt2_hi, bt2_lo);
    rpn_main<<<8192, 256, 0, stream>>>(
        x, b_base, b_cls, b_reg, btI, bt2_hi, bt2_lo, out);
}

// Round 4
// 603.107 us; speedup vs baseline: 1.2124x; 1.2124x over previous
//
#include <hip/hip_runtime.h>
#include <hip/hip_bf16.h>
#include <math.h>

// ---------------------------------------------------------------------------
// RPN fused kernel for MI355X (gfx950)
//   trunk : 3x3 conv 64->512 + bias + relu   (fp16 split-A 2-pass MFMA)
//   heads : 1x1 conv 512->9 (sigmoid) and 512->36 (linear), deltas masked by
//           score > 0.7, output [B,H,W,45] fp32
// Round 4: L1-BW fix. R3 was L1-bound (57 of ~64 B/cyc/CU: per-wave weight
//   stream 2KB/6-MFMA). Switch trunk to fp16 2-pass: w in ONE fp16 value
//   (2^-12 rel err), x split hi/lo fp16 (exact to 2^-24):
//     acc += xh*wh ; acc += xl*wh     -- B bytes/si-step halved to 16 B/lane,
//   MFMA count 3->2 passes. B demand 53 B/cyc < 64 ceiling; MFMA floor 145us.
//   Depth-8 register ring prefetch (slot = l, compile-time). M=32/wave,
//   64 acc AGPRs, launch_bounds(256,3).
// ---------------------------------------------------------------------------

typedef _Float16 fp16x8 __attribute__((ext_vector_type(8)));
typedef _Float16 fp16x4 __attribute__((ext_vector_type(4)));
typedef float    f32x4  __attribute__((ext_vector_type(4)));

#define SI_STEPS  144                   // 18 k-chunks x 8 n-subtiles
#define SI_SLOTS  152                   // +8 pad slots for prefetch overrun
#define BTI_ELEMS (SI_SLOTS * 256 * 8)  // trunk weights fp16, [si][tid][8]
#define BT2_ELEMS (48 * 512)            // head weights, [o][k] k-major

// ---------------------------------------------------------------------------
// prep: trunk weights -> fp16 [si][tid][8] (exact per-lane load order);
//       head weights  -> fp16 hi/lo [o][k]
// ---------------------------------------------------------------------------
__global__ __launch_bounds__(256) void rpn_prep(
    const float* __restrict__ wb,   // [3][3][64][512]
    const float* __restrict__ wc,   // [512][9]
    const float* __restrict__ wr,   // [512][36]
    _Float16* __restrict__ btI,
    _Float16* __restrict__ bt2_hi, _Float16* __restrict__ bt2_lo)
{
    int t = blockIdx.x * 256 + threadIdx.x;
    if (t < SI_STEPS * 256 * 8) {
        int j    = t & 7;
        int lane = (t >> 3) & 63;
        int wv   = (t >> 9) & 3;
        int si   = t >> 11;              // 0..143
        int s    = si >> 3;              // k-chunk 0..17
        int l    = si & 7;               // n-subtile 0..7
        int lr   = lane & 15;
        int q    = lane >> 4;
        int n    = wv * 128 + l * 16 + lr;
        int kg   = s * 32 + q * 8 + j;   // 0..575
        int tap  = kg >> 6, c = kg & 63; // k = (ky*3+kx)*64 + c
        float v  = wb[(tap * 64 + c) * 512 + n];
        btI[(si * 256 + wv * 64 + lane) * 8 + j] = (_Float16)v;
    } else if (t < SI_STEPS * 256 * 8 + BT2_ELEMS) {
        int jj = t - SI_STEPS * 256 * 8;
        int k = jj & 511;
        int o = jj >> 9;                 // 0..47
        float v = 0.f;
        if (o < 9)       v = wc[k * 9 + o];
        else if (o < 45) v = wr[k * 36 + (o - 9)];
        _Float16 h = (_Float16)v;
        bt2_hi[jj] = h;
        bt2_lo[jj] = (_Float16)(v - (float)h);
    }
}

// ---------------------------------------------------------------------------
// main fused kernel: 8192 workgroups x 256 threads
//   tile = 32 output positions (1 h-row x 32 w) x 512 channels
//   wave w owns channel slice [128w, 128w+128); per wave acc[2][8] = 64 AGPR
// LDS arena (29376 B), phase-overlapped:
//   phase1: xs_hi [3][34][72] fp16 @0 (14688 B), xs_lo @14688 (14688 B)
//   phase2: zbuf  float[32][48] @0 (6144 B),
//           fbuf per wave @6144 + w*4608: fh [32][36] fp16, fl +2304 B
// ---------------------------------------------------------------------------
#define XS_LO_OFF   14688
#define FB_OFF      6144
#define FB_PER_WAVE 4608
#define ARENA_BYTES 29376

__global__ __launch_bounds__(256, 3) void rpn_main(
    const float* __restrict__ x,        // [4][256][256][64]
    const float* __restrict__ b_base,   // [512]
    const float* __restrict__ b_cls,    // [9]
    const float* __restrict__ b_reg,    // [36]
    const _Float16* __restrict__ btI,
    const _Float16* __restrict__ bt2_hi, const _Float16* __restrict__ bt2_lo,
    float* __restrict__ out)            // [4][256][256][45]
{
    __shared__ char smem[ARENA_BYTES];
    _Float16* xs_hi = (_Float16*)smem;
    _Float16* xs_lo = (_Float16*)(smem + XS_LO_OFF);
    float*    zbuf  = (float*)smem;

    const int tid  = threadIdx.x;
    const int wave = tid >> 6;
    const int lane = tid & 63;
    const int q    = lane >> 4;     // 0..3
    const int lr   = lane & 15;     // 0..15
    const int n0   = wave * 128;    // wave's channel-slice base

    const int wg  = blockIdx.x;
    const int b   = wg >> 11;           // 2048 tiles per image
    const int rem = wg & 2047;
    const int h0  = rem >> 3;           // single h-row per tile
    const int w0  = (rem & 7) * 32;     // 32 w-positions per tile

    // ---- stage x patch (3 rows x 34 pos x 64 ch) as fp16 hi/lo ----
    for (int i = 0; i < 7; ++i) {
        int flat = tid + i * 256;
        if (flat < 3 * 34 * 16) {
            int cq  = flat & 15;          // channel quad
            int rp  = flat >> 4;          // 0..101
            int row = rp / 34;
            int pos = rp - row * 34;
            int hh  = h0 - 1 + row;
            int ww  = w0 - 1 + pos;
            fp16x4 h4, l4;
            if (hh >= 0 && hh < 256 && ww >= 0 && ww < 256) {
                const float4 v = *(const float4*)&x[(((b * 256 + hh) * 256 + ww) * 64 + cq * 4)];
                float vs[4] = {v.x, v.y, v.z, v.w};
                #pragma unroll
                for (int j = 0; j < 4; ++j) {
                    _Float16 h = (_Float16)vs[j];
                    h4[j] = h;
                    l4[j] = (_Float16)(vs[j] - (float)h);
                }
            } else {
                #pragma unroll
                for (int j = 0; j < 4; ++j) { h4[j] = (_Float16)0.f; l4[j] = (_Float16)0.f; }
            }
            int off = (row * 34 + pos) * 72 + cq * 4;
            *(fp16x4*)&xs_hi[off] = h4;
            *(fp16x4*)&xs_lo[off] = l4;
        }
    }
    __syncthreads();   // barrier 1: xs ready

    // ---- trunk K-loop: 144 si-steps, barrier-free, depth-8 weight prefetch ----
    f32x4 acc[2][8];
    #pragma unroll
    for (int km = 0; km < 2; ++km)
        #pragma unroll
        for (int l = 0; l < 8; ++l)
            acc[km][l] = (f32x4){0.f, 0.f, 0.f, 0.f};

    // per-lane weight stream base: 16 B per si-step
    const _Float16* bq = btI + (size_t)tid * 8;

    fp16x8 pf[8];
    #pragma unroll
    for (int p = 0; p < 8; ++p)
        pf[p] = *(const fp16x8*)(bq + (size_t)p * 2048);

    for (int s = 0; s < 18; ++s) {
        const int tap = s >> 1;
        const int ky  = tap / 3;
        const int kx  = tap - ky * 3;
        const int c0  = (s & 1) * 32 + q * 8;
        fp16x8 ah[2], al[2];
        #pragma unroll
        for (int km = 0; km < 2; ++km) {
            int pos  = (km << 4) + lr + kx;
            int off  = (ky * 34 + pos) * 72 + c0;
            ah[km] = *(const fp16x8*)&xs_hi[off];
            al[km] = *(const fp16x8*)&xs_lo[off];
        }
        #pragma unroll
        for (int l = 0; l < 8; ++l) {
            fp16x8 bh = pf[l];            // slot index (s*8+l)&7 == l
            // issue refill for si+8 into the slot just consumed
            {
                int nsi = s * 8 + l + 8;  // <= 151, pad slots allocated
                pf[l] = *(const fp16x8*)(bq + (size_t)nsi * 2048);
            }
            #pragma unroll
            for (int km = 0; km < 2; ++km)
                acc[km][l] = __builtin_amdgcn_mfma_f32_16x16x32_f16(ah[km], bh, acc[km][l], 0, 0, 0);
            #pragma unroll
            for (int km = 0; km < 2; ++km)
                acc[km][l] = __builtin_amdgcn_mfma_f32_16x16x32_f16(al[km], bh, acc[km][l], 0, 0, 0);
        }
    }

    __syncthreads();   // barrier 2: xs dead, safe to reuse arena

    // zero the z accumulation buffer
    for (int i = tid; i < 32 * 48; i += 256) zbuf[i] = 0.f;
    __syncthreads();   // barrier 3: zbuf zeroed

    // ---- fused 1x1 heads: per-wave k-slice GEMM feat[32][128] x w2[128][48] ----
    _Float16* fh = (_Float16*)(smem + FB_OFF + wave * FB_PER_WAVE);
    _Float16* fl = fh + 32 * 36;

    f32x4 acc2[2][3];
    #pragma unroll
    for (int km = 0; km < 2; ++km)
        #pragma unroll
        for (int ns = 0; ns < 3; ++ns)
            acc2[km][ns] = (f32x4){0.f, 0.f, 0.f, 0.f};

    for (int sub = 0; sub < 4; ++sub) {       // 4 k-chunks of 32 within the slice
        // dump this wave's 32-channel slice of feat (bias+relu, fp16 hi/lo)
        #pragma unroll
        for (int lh = 0; lh < 2; ++lh) {
            int l = sub * 2 + lh;
            float bias = b_base[n0 + l * 16 + lr];
            #pragma unroll
            for (int km = 0; km < 2; ++km) {
                #pragma unroll
                for (int r = 0; r < 4; ++r) {
                    float v = acc[km][l][r] + bias;
                    v = v > 0.f ? v : 0.f;
                    _Float16 h = (_Float16)v;
                    int row = km * 16 + q * 4 + r;
                    int col = lh * 16 + lr;
                    fh[row * 36 + col] = h;
                    fl[row * 36 + col] = (_Float16)(v - (float)h);
                }
            }
        }
        asm volatile("s_waitcnt lgkmcnt(0)" ::: "memory");  // wave-local RAW fence

        // A-frags: feat rows, k-local = q*8..q*8+7 (8-byte aligned -> 2x b64)
        fp16x8 fah[2], fal[2];
        #pragma unroll
        for (int km = 0; km < 2; ++km) {
            int off = (km * 16 + lr) * 36 + q * 8;
            union { fp16x8 v8; fp16x4 v4[2]; } uh, ul;
            uh.v4[0] = *(const fp16x4*)&fh[off];
            uh.v4[1] = *(const fp16x4*)&fh[off + 4];
            ul.v4[0] = *(const fp16x4*)&fl[off];
            ul.v4[1] = *(const fp16x4*)&fl[off + 4];
            fah[km] = uh.v8;
            fal[km] = ul.v8;
        }

        const int kg = n0 + sub * 32 + q * 8;   // global k for B frags
        // ns = 0 (contains the 9 score cols): 3-pass hi/lo
        {
            int eo = (0 * 16 + lr) * 512 + kg;
            fp16x8 wh = *(const fp16x8*)&bt2_hi[eo];
            fp16x8 wl = *(const fp16x8*)&bt2_lo[eo];
            #pragma unroll
            for (int km = 0; km < 2; ++km)
                acc2[km][0] = __builtin_amdgcn_mfma_f32_16x16x32_f16(fah[km], wh, acc2[km][0], 0, 0, 0);
            #pragma unroll
            for (int km = 0; km < 2; ++km)
                acc2[km][0] = __builtin_amdgcn_mfma_f32_16x16x32_f16(fah[km], wl, acc2[km][0], 0, 0, 0);
            #pragma unroll
            for (int km = 0; km < 2; ++km)
                acc2[km][0] = __builtin_amdgcn_mfma_f32_16x16x32_f16(fal[km], wh, acc2[km][0], 0, 0, 0);
        }
        // ns = 1,2 (pure delta cols): 2-pass (w fp16 single, x hi+lo)
        #pragma unroll
        for (int ns = 1; ns < 3; ++ns) {
            int eo = (ns * 16 + lr) * 512 + kg;
            fp16x8 wh = *(const fp16x8*)&bt2_hi[eo];
            #pragma unroll
            for (int km = 0; km < 2; ++km)
                acc2[km][ns] = __builtin_amdgcn_mfma_f32_16x16x32_f16(fah[km], wh, acc2[km][ns], 0, 0, 0);
            #pragma unroll
            for (int km = 0; km < 2; ++km)
                acc2[km][ns] = __builtin_amdgcn_mfma_f32_16x16x32_f16(fal[km], wh, acc2[km][ns], 0, 0, 0);
        }
    }

    // k-slice reduction across waves
    #pragma unroll
    for (int km = 0; km < 2; ++km)
        #pragma unroll
        for (int ns = 0; ns < 3; ++ns)
            #pragma unroll
            for (int r = 0; r < 4; ++r) {
                int row = km * 16 + q * 4 + r;
                int col = ns * 16 + lr;
                atomicAdd(&zbuf[row * 48 + col], acc2[km][ns][r]);
            }
    __syncthreads();   // barrier 4: z complete

    // ---- epilogue: sigmoid, threshold mask, store ----
    for (int i = tid; i < 32 * 45; i += 256) {
        int m = i / 45;
        int o = i - m * 45;
        float z = zbuf[m * 48 + o];
        float v;
        if (o < 9) {
            v = 1.f / (1.f + expf(-(z + b_cls[o])));
        } else {
            int d = o - 9;
            int a = d >> 2;
            float s = 1.f / (1.f + expf(-(zbuf[m * 48 + a] + b_cls[a])));
            v = (s > 0.7f) ? (z + b_reg[d]) : 0.f;
        }
        out[(((b * 256 + h0) * 256) + w0 + m) * 45 + o] = v;
    }
}

// ---------------------------------------------------------------------------
extern "C" void kernel_launch(void* const* d_in, const int* in_sizes, int n_in,
                              void* d_out, int out_size, void* d_ws, size_t ws_size,
                              hipStream_t stream)
{
    const float* x      = (const float*)d_in[0];
    const float* w_base = (const float*)d_in[1];
    const float* b_base = (const float*)d_in[2];
    const float* w_cls  = (const float*)d_in[3];
    const float* b_cls  = (const float*)d_in[4];
    const float* w_reg  = (const float*)d_in[5];
    const float* b_reg  = (const float*)d_in[6];
    float* out = (float*)d_out;

    _Float16* btI    = (_Float16*)d_ws;
    _Float16* bt2_hi = btI + BTI_ELEMS;
    _Float16* bt2_lo = bt2_hi + BT2_ELEMS;

    rpn_prep<<<(SI_STEPS * 256 * 8 + BT2_ELEMS + 255) / 256, 256, 0, stream>>>(
        w_base, w_cls, w_reg, btI, bt2_hi, bt2_lo);
    rpn_main<<<8192, 256, 0, stream>>>(
        x, b_base, b_cls, b_reg, btI, bt2_hi, bt2_lo, out);
}

// Round 6
// 406.937 us; speedup vs baseline: 1.7968x; 1.4821x over previous
//
#include <hip/hip_runtime.h>
#include <hip/hip_bf16.h>
#include <math.h>

// ---------------------------------------------------------------------------
// RPN fused kernel for MI355X (gfx950)
//   trunk : 3x3 conv 64->512 + bias + relu   (fp16 split-A 2-pass MFMA)
//   heads : 1x1 conv 512->9 (sigmoid) and 512->36 (linear), deltas masked by
//           score > 0.7, output [B,H,W,45] fp32
// Round 6:
//  (a) DETERMINISM FIX: R5's replay failure (absmax 0.57 post-timing) was a
//      borderline anchor flipping across score>0.7 due to nondeterministic FP
//      order in the head's cross-wave LDS atomicAdd reduction. Replaced with a
//      4-stage barrier-ordered reduction -> kernel is bitwise deterministic.
//  (b) PIPELINE FIX: R5's K-loop was effectively single-buffered (DMA for s+1
//      issued only after MFMAs consumed slot s from LDS -> DMA latency exposed
//      every step). Now B-frags are read LDS->VGPR first (16 ds_read_b128),
//      lgkmcnt(0), DMA for s+1 issued, THEN 64 MFMAs run from registers --
//      DMA overlaps the full MFMA block.
// ---------------------------------------------------------------------------

typedef _Float16 fp16x8 __attribute__((ext_vector_type(8)));
typedef _Float16 fp16x4 __attribute__((ext_vector_type(4)));
typedef float    f32x4  __attribute__((ext_vector_type(4)));

#define BT_ELEMS  (18 * 32 * 64 * 8)    // 294912 trunk weights fp16
#define BT2_ELEMS (48 * 512)            // head weights, [o][k] k-major

__device__ __forceinline__ void gl_lds16(const void* g, void* l) {
    __builtin_amdgcn_global_load_lds(
        (const __attribute__((address_space(1))) void*)g,
        (__attribute__((address_space(3))) void*)l, 16, 0, 0);
}

// ---------------------------------------------------------------------------
// prep: trunk weights -> fp16 bt[s][j=wv*8+l][lane][8]  (exact LDS staging
//       order: wave wv's frag for subtile l, lane, k-elem e)
//       head weights  -> fp16 hi/lo [o][k]
// ---------------------------------------------------------------------------
__global__ __launch_bounds__(256) void rpn_prep(
    const float* __restrict__ wb,   // [3][3][64][512]
    const float* __restrict__ wc,   // [512][9]
    const float* __restrict__ wr,   // [512][36]
    _Float16* __restrict__ btI,
    _Float16* __restrict__ bt2_hi, _Float16* __restrict__ bt2_lo)
{
    int t = blockIdx.x * 256 + threadIdx.x;
    if (t < BT_ELEMS) {
        int e    = t & 7;
        int lane = (t >> 3) & 63;
        int j    = (t >> 9) & 31;
        int s    = t >> 14;              // 0..17
        int wv   = j >> 3, l = j & 7;
        int lr   = lane & 15, q = lane >> 4;
        int n    = wv * 128 + l * 16 + lr;
        int k    = s * 32 + q * 8 + e;   // 0..575
        int tap  = k >> 6, c = k & 63;   // k = (ky*3+kx)*64 + c
        btI[t] = (_Float16)wb[(tap * 64 + c) * 512 + n];
    } else if (t < BT_ELEMS + BT2_ELEMS) {
        int jj = t - BT_ELEMS;
        int k = jj & 511;
        int o = jj >> 9;                 // 0..47
        float v = 0.f;
        if (o < 9)       v = wc[k * 9 + o];
        else if (o < 45) v = wr[k * 36 + (o - 9)];
        _Float16 h = (_Float16)v;
        bt2_hi[jj] = h;
        bt2_lo[jj] = (_Float16)(v - (float)h);
    }
}

// ---------------------------------------------------------------------------
// main fused kernel: 4096 workgroups x 256 threads
//   tile = 64 output positions (2 h-rows x 32 w) x 512 channels
//   wave w owns channel slice [128w, 128w+128); acc[4][8] = 128 AGPR
// LDS arena (71936 B):
//   [0, 32768)        B-slots: wave w owns [w*8192, w*8192+8192)
//   [32768, +19584)   xs_hi [4][34][72] fp16
//   [52352, +19584)   xs_lo
//   head phase reuses [0, 49152): zbuf float[64][48] @0,
//   fbuf per wave @12288 + w*9216 (fh [64][36] fp16, fl +4608 B)
// ---------------------------------------------------------------------------
#define BS_BYTES    32768
#define XS_HI_OFF   32768
#define XS_LO_OFF   52352
#define FB_OFF      12288
#define FB_PER_WAVE 9216
#define ARENA_BYTES 71936

__global__ __launch_bounds__(256, 2) void rpn_main(
    const float* __restrict__ x,        // [4][256][256][64]
    const float* __restrict__ b_base,   // [512]
    const float* __restrict__ b_cls,    // [9]
    const float* __restrict__ b_reg,    // [36]
    const _Float16* __restrict__ btI,
    const _Float16* __restrict__ bt2_hi, const _Float16* __restrict__ bt2_lo,
    float* __restrict__ out)            // [4][256][256][45]
{
    __shared__ char smem[ARENA_BYTES];
    _Float16* xs_hi = (_Float16*)(smem + XS_HI_OFF);
    _Float16* xs_lo = (_Float16*)(smem + XS_LO_OFF);
    float*    zbuf  = (float*)smem;

    const int tid  = threadIdx.x;
    const int wave = tid >> 6;
    const int lane = tid & 63;
    const int q    = lane >> 4;     // 0..3
    const int lr   = lane & 15;     // 0..15
    const int n0   = wave * 128;    // wave's channel-slice base

    const int wg  = blockIdx.x;
    const int b   = wg >> 10;           // 1024 tiles per image
    const int rem = wg & 1023;
    const int h0  = (rem >> 3) * 2;     // 2 h-rows per tile
    const int w0  = (rem & 7) * 32;     // 32 w-positions per tile

    // wave-private B staging pointers
    char* bsw = smem + wave * 8192;                       // LDS slot
    const char* gB0 = (const char*)btI + wave * 8192 + lane * 16;

    // ---- issue B stage for s=0 (latency overlaps x staging) ----
    #pragma unroll
    for (int i = 0; i < 8; ++i)
        gl_lds16(gB0 + i * 1024, bsw + i * 1024);

    // ---- stage x patch (4 rows x 34 pos x 64 ch) as fp16 hi/lo ----
    for (int i = 0; i < 9; ++i) {
        int flat = tid + i * 256;
        if (flat < 4 * 34 * 16) {
            int cq  = flat & 15;          // channel quad
            int rp  = flat >> 4;          // 0..135
            int row = rp / 34;
            int pos = rp - row * 34;
            int hh  = h0 - 1 + row;
            int ww  = w0 - 1 + pos;
            fp16x4 h4, l4;
            if (hh >= 0 && hh < 256 && ww >= 0 && ww < 256) {
                const float4 v = *(const float4*)&x[(((b * 256 + hh) * 256 + ww) * 64 + cq * 4)];
                float vs[4] = {v.x, v.y, v.z, v.w};
                #pragma unroll
                for (int j = 0; j < 4; ++j) {
                    _Float16 h = (_Float16)vs[j];
                    h4[j] = h;
                    l4[j] = (_Float16)(vs[j] - (float)h);
                }
            } else {
                #pragma unroll
                for (int j = 0; j < 4; ++j) { h4[j] = (_Float16)0.f; l4[j] = (_Float16)0.f; }
            }
            int off = (row * 34 + pos) * 72 + cq * 4;
            *(fp16x4*)&xs_hi[off] = h4;
            *(fp16x4*)&xs_lo[off] = l4;
        }
    }
    asm volatile("s_waitcnt vmcnt(0)" ::: "memory");  // B0 landed
    __syncthreads();   // barrier 1: xs + B0 ready

    // ---- trunk K-loop: 18 s-steps, barrier-free, LDS-DMA weight pipeline ----
    f32x4 acc[4][8];
    #pragma unroll
    for (int km = 0; km < 4; ++km)
        #pragma unroll
        for (int l = 0; l < 8; ++l)
            acc[km][l] = (f32x4){0.f, 0.f, 0.f, 0.f};

    const _Float16* bsr = (const _Float16*)(bsw + lane * 16);  // frag base

    for (int s = 0; s < 18; ++s) {
        const int tap = s >> 1;
        const int ky  = tap / 3;
        const int kx  = tap - ky * 3;
        const int c0  = (s & 1) * 32 + q * 8;
        // A-frags from xs (disjoint from B slots -> safe before vmcnt wait)
        fp16x8 ah[4], al[4];
        #pragma unroll
        for (int km = 0; km < 4; ++km) {
            int rowp = (km >> 1) + ky;
            int pos  = ((km & 1) << 4) + lr + kx;
            int off  = (rowp * 34 + pos) * 72 + c0;
            ah[km] = *(const fp16x8*)&xs_hi[off];
            al[km] = *(const fp16x8*)&xs_lo[off];
        }
        asm volatile("s_waitcnt vmcnt(0)" ::: "memory");  // B(s) landed
        // B-frags LDS -> VGPR (frees the slot for the next DMA)
        fp16x8 bh[8];
        #pragma unroll
        for (int l = 0; l < 8; ++l)
            bh[l] = *(const fp16x8*)(bsr + l * 512);       // l*1024 bytes
        asm volatile("s_waitcnt lgkmcnt(0)" ::: "memory"); // frag reads retired
        if (s < 17) {
            // slot free: issue DMA for s+1 NOW; it overlaps the MFMA block
            const char* gBs = gB0 + (size_t)(s + 1) * BS_BYTES;
            #pragma unroll
            for (int i = 0; i < 8; ++i)
                gl_lds16(gBs + i * 1024, bsw + i * 1024);
        }
        // 64 MFMAs from registers
        #pragma unroll
        for (int l = 0; l < 8; ++l) {
            acc[0][l] = __builtin_amdgcn_mfma_f32_16x16x32_f16(ah[0], bh[l], acc[0][l], 0, 0, 0);
            acc[1][l] = __builtin_amdgcn_mfma_f32_16x16x32_f16(ah[1], bh[l], acc[1][l], 0, 0, 0);
            acc[2][l] = __builtin_amdgcn_mfma_f32_16x16x32_f16(ah[2], bh[l], acc[2][l], 0, 0, 0);
            acc[3][l] = __builtin_amdgcn_mfma_f32_16x16x32_f16(ah[3], bh[l], acc[3][l], 0, 0, 0);
            acc[0][l] = __builtin_amdgcn_mfma_f32_16x16x32_f16(al[0], bh[l], acc[0][l], 0, 0, 0);
            acc[1][l] = __builtin_amdgcn_mfma_f32_16x16x32_f16(al[1], bh[l], acc[1][l], 0, 0, 0);
            acc[2][l] = __builtin_amdgcn_mfma_f32_16x16x32_f16(al[2], bh[l], acc[2][l], 0, 0, 0);
            acc[3][l] = __builtin_amdgcn_mfma_f32_16x16x32_f16(al[3], bh[l], acc[3][l], 0, 0, 0);
        }
    }

    __syncthreads();   // barrier 2: trunk done (all DMAs drained), arena reusable

    // ---- fused 1x1 heads: per-wave k-slice GEMM feat[64][128] x w2[128][48] ----
    _Float16* fh = (_Float16*)(smem + FB_OFF + wave * FB_PER_WAVE);
    _Float16* fl = fh + 64 * 36;

    f32x4 acc2[4][3];
    #pragma unroll
    for (int km = 0; km < 4; ++km)
        #pragma unroll
        for (int ns = 0; ns < 3; ++ns)
            acc2[km][ns] = (f32x4){0.f, 0.f, 0.f, 0.f};

    for (int sub = 0; sub < 4; ++sub) {       // 4 k-chunks of 32 within the slice
        // dump this wave's 32-channel slice of feat (bias+relu, fp16 hi/lo)
        #pragma unroll
        for (int lh = 0; lh < 2; ++lh) {
            int l = sub * 2 + lh;
            float bias = b_base[n0 + l * 16 + lr];
            #pragma unroll
            for (int km = 0; km < 4; ++km) {
                #pragma unroll
                for (int r = 0; r < 4; ++r) {
                    float v = acc[km][l][r] + bias;
                    v = v > 0.f ? v : 0.f;
                    _Float16 h = (_Float16)v;
                    int row = km * 16 + q * 4 + r;
                    int col = lh * 16 + lr;
                    fh[row * 36 + col] = h;
                    fl[row * 36 + col] = (_Float16)(v - (float)h);
                }
            }
        }
        asm volatile("s_waitcnt lgkmcnt(0)" ::: "memory");  // wave-local RAW fence

        // A-frags: feat rows, k-local = q*8..q*8+7 (8-byte aligned -> 2x b64)
        fp16x8 fah[4], fal[4];
        #pragma unroll
        for (int km = 0; km < 4; ++km) {
            int off = (km * 16 + lr) * 36 + q * 8;
            union { fp16x8 v8; fp16x4 v4[2]; } uh, ul;
            uh.v4[0] = *(const fp16x4*)&fh[off];
            uh.v4[1] = *(const fp16x4*)&fh[off + 4];
            ul.v4[0] = *(const fp16x4*)&fl[off];
            ul.v4[1] = *(const fp16x4*)&fl[off + 4];
            fah[km] = uh.v8;
            fal[km] = ul.v8;
        }

        const int kg = n0 + sub * 32 + q * 8;   // global k for B frags
        // ns = 0 (contains the 9 score cols): 3-pass hi/lo
        {
            int eo = (0 * 16 + lr) * 512 + kg;
            fp16x8 wh = *(const fp16x8*)&bt2_hi[eo];
            fp16x8 wl = *(const fp16x8*)&bt2_lo[eo];
            #pragma unroll
            for (int km = 0; km < 4; ++km)
                acc2[km][0] = __builtin_amdgcn_mfma_f32_16x16x32_f16(fah[km], wh, acc2[km][0], 0, 0, 0);
            #pragma unroll
            for (int km = 0; km < 4; ++km)
                acc2[km][0] = __builtin_amdgcn_mfma_f32_16x16x32_f16(fah[km], wl, acc2[km][0], 0, 0, 0);
            #pragma unroll
            for (int km = 0; km < 4; ++km)
                acc2[km][0] = __builtin_amdgcn_mfma_f32_16x16x32_f16(fal[km], wh, acc2[km][0], 0, 0, 0);
        }
        // ns = 1,2 (pure delta cols): 2-pass (w fp16 single, x hi+lo)
        #pragma unroll
        for (int ns = 1; ns < 3; ++ns) {
            int eo = (ns * 16 + lr) * 512 + kg;
            fp16x8 wh = *(const fp16x8*)&bt2_hi[eo];
            #pragma unroll
            for (int km = 0; km < 4; ++km)
                acc2[km][ns] = __builtin_amdgcn_mfma_f32_16x16x32_f16(fah[km], wh, acc2[km][ns], 0, 0, 0);
            #pragma unroll
            for (int km = 0; km < 4; ++km)
                acc2[km][ns] = __builtin_amdgcn_mfma_f32_16x16x32_f16(fal[km], wh, acc2[km][ns], 0, 0, 0);
        }
    }

    // ---- deterministic staged cross-wave k-reduction (replaces atomicAdd:
    //      fixed FP summation order -> bitwise-identical output every launch;
    //      zbuf [0,12288) is disjoint from all fbuf slots, so stage 0 may
    //      start while other waves are still in their sub-loop) ----
    for (int w = 0; w < 4; ++w) {
        if (wave == w) {
            #pragma unroll
            for (int km = 0; km < 4; ++km)
                #pragma unroll
                for (int ns = 0; ns < 3; ++ns)
                    #pragma unroll
                    for (int r = 0; r < 4; ++r) {
                        int row = km * 16 + q * 4 + r;
                        int col = ns * 16 + lr;
                        float v = acc2[km][ns][r];
                        if (w == 0) zbuf[row * 48 + col] = v;
                        else        zbuf[row * 48 + col] += v;
                    }
        }
        __syncthreads();   // stage w complete before stage w+1 / epilogue
    }

    // ---- epilogue: sigmoid, threshold mask, store ----
    for (int i = tid; i < 64 * 45; i += 256) {
        int m = i / 45;
        int o = i - m * 45;
        float z = zbuf[m * 48 + o];
        float v;
        if (o < 9) {
            v = 1.f / (1.f + expf(-(z + b_cls[o])));
        } else {
            int d = o - 9;
            int a = d >> 2;
            float s = 1.f / (1.f + expf(-(zbuf[m * 48 + a] + b_cls[a])));
            v = (s > 0.7f) ? (z + b_reg[d]) : 0.f;
        }
        int mh = m >> 5, mw = m & 31;
        out[(((b * 256 + h0 + mh) * 256) + w0 + mw) * 45 + o] = v;
    }
}

// ---------------------------------------------------------------------------
extern "C" void kernel_launch(void* const* d_in, const int* in_sizes, int n_in,
                              void* d_out, int out_size, void* d_ws, size_t ws_size,
                              hipStream_t stream)
{
    const float* x      = (const float*)d_in[0];
    const float* w_base = (const float*)d_in[1];
    const float* b_base = (const float*)d_in[2];
    const float* w_cls  = (const float*)d_in[3];
    const float* b_cls  = (const float*)d_in[4];
    const float* w_reg  = (const float*)d_in[5];
    const float* b_reg  = (const float*)d_in[6];
    float* out = (float*)d_out;

    _Float16* btI    = (_Float16*)d_ws;
    _Float16* bt2_hi = btI + BT_ELEMS;
    _Float16* bt2_lo = bt2_hi + BT2_ELEMS;

    rpn_prep<<<(BT_ELEMS + BT2_ELEMS + 255) / 256, 256, 0, stream>>>(
        w_base, w_cls, w_reg, btI, bt2_hi, bt2_lo);
    rpn_main<<<4096, 256, 0, stream>>>(
        x, b_base, b_cls, b_reg, btI, bt2_hi, bt2_lo, out);
}

// Round 7
// 363.317 us; speedup vs baseline: 2.0125x; 1.1201x over previous
//
#include <hip/hip_runtime.h>
#include <hip/hip_bf16.h>
#include <math.h>

// ---------------------------------------------------------------------------
// RPN fused kernel for MI355X (gfx950)
//   trunk : 3x3 conv 64->512 + bias + relu   (fp16 single-pass MFMA)
//   heads : 1x1 conv 512->9 (sigmoid) and 512->36 (linear), deltas masked by
//           score > 0.7, output [B,H,W,45] fp32
// Round 7: halve trunk MFMA work. R6 hit 44% MfmaUtil vs a 164us floor; the
//   remaining lever is the MFMA count. Trunk goes single-pass fp16
//   (x_h * w_h only): score-logit err 4.4e-5 -> 6e-5 (w-quant already
//   dominated; absmax was bit-identical across R1-R6 numerics spanning this
//   range). Floor 164 -> 88 us. xs_lo staging dropped (VALU + LDS halved in
//   staging; arena 72 -> 52 KB). Head keeps feat hi/lo 3-pass for scores,
//   2-pass for deltas. Deterministic staged reduction kept from R6.
// ---------------------------------------------------------------------------

typedef _Float16 fp16x8 __attribute__((ext_vector_type(8)));
typedef _Float16 fp16x4 __attribute__((ext_vector_type(4)));
typedef float    f32x4  __attribute__((ext_vector_type(4)));

#define BT_ELEMS  (18 * 32 * 64 * 8)    // 294912 trunk weights fp16
#define BT2_ELEMS (48 * 512)            // head weights, [o][k] k-major

__device__ __forceinline__ void gl_lds16(const void* g, void* l) {
    __builtin_amdgcn_global_load_lds(
        (const __attribute__((address_space(1))) void*)g,
        (__attribute__((address_space(3))) void*)l, 16, 0, 0);
}

// ---------------------------------------------------------------------------
// prep: trunk weights -> fp16 bt[s][j=wv*8+l][lane][8]  (exact LDS staging
//       order); head weights -> fp16 hi/lo [o][k]
// ---------------------------------------------------------------------------
__global__ __launch_bounds__(256) void rpn_prep(
    const float* __restrict__ wb,   // [3][3][64][512]
    const float* __restrict__ wc,   // [512][9]
    const float* __restrict__ wr,   // [512][36]
    _Float16* __restrict__ btI,
    _Float16* __restrict__ bt2_hi, _Float16* __restrict__ bt2_lo)
{
    int t = blockIdx.x * 256 + threadIdx.x;
    if (t < BT_ELEMS) {
        int e    = t & 7;
        int lane = (t >> 3) & 63;
        int j    = (t >> 9) & 31;
        int s    = t >> 14;              // 0..17
        int wv   = j >> 3, l = j & 7;
        int lr   = lane & 15, q = lane >> 4;
        int n    = wv * 128 + l * 16 + lr;
        int k    = s * 32 + q * 8 + e;   // 0..575
        int tap  = k >> 6, c = k & 63;   // k = (ky*3+kx)*64 + c
        btI[t] = (_Float16)wb[(tap * 64 + c) * 512 + n];
    } else if (t < BT_ELEMS + BT2_ELEMS) {
        int jj = t - BT_ELEMS;
        int k = jj & 511;
        int o = jj >> 9;                 // 0..47
        float v = 0.f;
        if (o < 9)       v = wc[k * 9 + o];
        else if (o < 45) v = wr[k * 36 + (o - 9)];
        _Float16 h = (_Float16)v;
        bt2_hi[jj] = h;
        bt2_lo[jj] = (_Float16)(v - (float)h);
    }
}

// ---------------------------------------------------------------------------
// main fused kernel: 4096 workgroups x 256 threads
//   tile = 64 output positions (2 h-rows x 32 w) x 512 channels
//   wave w owns channel slice [128w, 128w+128); acc[4][8] = 128 AGPR
// LDS arena (52352 B):
//   [0, 32768)        B-slots: wave w owns [w*8192, w*8192+8192)
//   [32768, +19584)   xs_hi [4][34][72] fp16
//   head phase reuses [0, 49152): zbuf float[64][48] @0,
//   fbuf per wave @12288 + w*9216 (fh [64][36] fp16, fl +4608 B)
// ---------------------------------------------------------------------------
#define BS_BYTES    32768
#define XS_HI_OFF   32768
#define FB_OFF      12288
#define FB_PER_WAVE 9216
#define ARENA_BYTES 52352

__global__ __launch_bounds__(256, 2) void rpn_main(
    const float* __restrict__ x,        // [4][256][256][64]
    const float* __restrict__ b_base,   // [512]
    const float* __restrict__ b_cls,    // [9]
    const float* __restrict__ b_reg,    // [36]
    const _Float16* __restrict__ btI,
    const _Float16* __restrict__ bt2_hi, const _Float16* __restrict__ bt2_lo,
    float* __restrict__ out)            // [4][256][256][45]
{
    __shared__ char smem[ARENA_BYTES];
    _Float16* xs_hi = (_Float16*)(smem + XS_HI_OFF);
    float*    zbuf  = (float*)smem;

    const int tid  = threadIdx.x;
    const int wave = tid >> 6;
    const int lane = tid & 63;
    const int q    = lane >> 4;     // 0..3
    const int lr   = lane & 15;     // 0..15
    const int n0   = wave * 128;    // wave's channel-slice base

    const int wg  = blockIdx.x;
    const int b   = wg >> 10;           // 1024 tiles per image
    const int rem = wg & 1023;
    const int h0  = (rem >> 3) * 2;     // 2 h-rows per tile
    const int w0  = (rem & 7) * 32;     // 32 w-positions per tile

    // wave-private B staging pointers
    char* bsw = smem + wave * 8192;                       // LDS slot
    const char* gB0 = (const char*)btI + wave * 8192 + lane * 16;

    // ---- issue B stage for s=0 (latency overlaps x staging) ----
    #pragma unroll
    for (int i = 0; i < 8; ++i)
        gl_lds16(gB0 + i * 1024, bsw + i * 1024);

    // ---- stage x patch (4 rows x 34 pos x 64 ch) as fp16 (single) ----
    for (int i = 0; i < 9; ++i) {
        int flat = tid + i * 256;
        if (flat < 4 * 34 * 16) {
            int cq  = flat & 15;          // channel quad
            int rp  = flat >> 4;          // 0..135
            int row = rp / 34;
            int pos = rp - row * 34;
            int hh  = h0 - 1 + row;
            int ww  = w0 - 1 + pos;
            fp16x4 h4;
            if (hh >= 0 && hh < 256 && ww >= 0 && ww < 256) {
                const float4 v = *(const float4*)&x[(((b * 256 + hh) * 256 + ww) * 64 + cq * 4)];
                h4[0] = (_Float16)v.x; h4[1] = (_Float16)v.y;
                h4[2] = (_Float16)v.z; h4[3] = (_Float16)v.w;
            } else {
                #pragma unroll
                for (int j = 0; j < 4; ++j) h4[j] = (_Float16)0.f;
            }
            *(fp16x4*)&xs_hi[(row * 34 + pos) * 72 + cq * 4] = h4;
        }
    }
    asm volatile("s_waitcnt vmcnt(0)" ::: "memory");  // B0 landed
    __syncthreads();   // barrier 1: xs + B0 ready

    // ---- trunk K-loop: 18 s-steps, barrier-free, LDS-DMA weight pipeline ----
    f32x4 acc[4][8];
    #pragma unroll
    for (int km = 0; km < 4; ++km)
        #pragma unroll
        for (int l = 0; l < 8; ++l)
            acc[km][l] = (f32x4){0.f, 0.f, 0.f, 0.f};

    const _Float16* bsr = (const _Float16*)(bsw + lane * 16);  // frag base

    for (int s = 0; s < 18; ++s) {
        const int tap = s >> 1;
        const int ky  = tap / 3;
        const int kx  = tap - ky * 3;
        const int c0  = (s & 1) * 32 + q * 8;
        // A-frags from xs (disjoint from B slots -> safe before vmcnt wait)
        fp16x8 ah[4];
        #pragma unroll
        for (int km = 0; km < 4; ++km) {
            int rowp = (km >> 1) + ky;
            int pos  = ((km & 1) << 4) + lr + kx;
            ah[km] = *(const fp16x8*)&xs_hi[(rowp * 34 + pos) * 72 + c0];
        }
        asm volatile("s_waitcnt vmcnt(0)" ::: "memory");  // B(s) landed
        // B-frags LDS -> VGPR (frees the slot for the next DMA)
        fp16x8 bh[8];
        #pragma unroll
        for (int l = 0; l < 8; ++l)
            bh[l] = *(const fp16x8*)(bsr + l * 512);       // l*1024 bytes
        asm volatile("s_waitcnt lgkmcnt(0)" ::: "memory"); // frag reads retired
        if (s < 17) {
            // slot free: issue DMA for s+1 NOW; it overlaps the MFMA block
            const char* gBs = gB0 + (size_t)(s + 1) * BS_BYTES;
            #pragma unroll
            for (int i = 0; i < 8; ++i)
                gl_lds16(gBs + i * 1024, bsw + i * 1024);
        }
        // 32 MFMAs from registers (single-pass: x_h * w_h)
        #pragma unroll
        for (int l = 0; l < 8; ++l) {
            acc[0][l] = __builtin_amdgcn_mfma_f32_16x16x32_f16(ah[0], bh[l], acc[0][l], 0, 0, 0);
            acc[1][l] = __builtin_amdgcn_mfma_f32_16x16x32_f16(ah[1], bh[l], acc[1][l], 0, 0, 0);
            acc[2][l] = __builtin_amdgcn_mfma_f32_16x16x32_f16(ah[2], bh[l], acc[2][l], 0, 0, 0);
            acc[3][l] = __builtin_amdgcn_mfma_f32_16x16x32_f16(ah[3], bh[l], acc[3][l], 0, 0, 0);
        }
    }

    __syncthreads();   // barrier 2: trunk done (all DMAs drained), arena reusable

    // ---- fused 1x1 heads: per-wave k-slice GEMM feat[64][128] x w2[128][48] ----
    _Float16* fh = (_Float16*)(smem + FB_OFF + wave * FB_PER_WAVE);
    _Float16* fl = fh + 64 * 36;

    f32x4 acc2[4][3];
    #pragma unroll
    for (int km = 0; km < 4; ++km)
        #pragma unroll
        for (int ns = 0; ns < 3; ++ns)
            acc2[km][ns] = (f32x4){0.f, 0.f, 0.f, 0.f};

    for (int sub = 0; sub < 4; ++sub) {       // 4 k-chunks of 32 within the slice
        // dump this wave's 32-channel slice of feat (bias+relu, fp16 hi/lo)
        #pragma unroll
        for (int lh = 0; lh < 2; ++lh) {
            int l = sub * 2 + lh;
            float bias = b_base[n0 + l * 16 + lr];
            #pragma unroll
            for (int km = 0; km < 4; ++km) {
                #pragma unroll
                for (int r = 0; r < 4; ++r) {
                    float v = acc[km][l][r] + bias;
                    v = v > 0.f ? v : 0.f;
                    _Float16 h = (_Float16)v;
                    int row = km * 16 + q * 4 + r;
                    int col = lh * 16 + lr;
                    fh[row * 36 + col] = h;
                    fl[row * 36 + col] = (_Float16)(v - (float)h);
                }
            }
        }
        asm volatile("s_waitcnt lgkmcnt(0)" ::: "memory");  // wave-local RAW fence

        // A-frags: feat rows, k-local = q*8..q*8+7 (8-byte aligned -> 2x b64)
        fp16x8 fah[4], fal[4];
        #pragma unroll
        for (int km = 0; km < 4; ++km) {
            int off = (km * 16 + lr) * 36 + q * 8;
            union { fp16x8 v8; fp16x4 v4[2]; } uh, ul;
            uh.v4[0] = *(const fp16x4*)&fh[off];
            uh.v4[1] = *(const fp16x4*)&fh[off + 4];
            ul.v4[0] = *(const fp16x4*)&fl[off];
            ul.v4[1] = *(const fp16x4*)&fl[off + 4];
            fah[km] = uh.v8;
            fal[km] = ul.v8;
        }

        const int kg = n0 + sub * 32 + q * 8;   // global k for B frags
        // ns = 0 (contains the 9 score cols): 3-pass hi/lo
        {
            int eo = (0 * 16 + lr) * 512 + kg;
            fp16x8 wh = *(const fp16x8*)&bt2_hi[eo];
            fp16x8 wl = *(const fp16x8*)&bt2_lo[eo];
            #pragma unroll
            for (int km = 0; km < 4; ++km)
                acc2[km][0] = __builtin_amdgcn_mfma_f32_16x16x32_f16(fah[km], wh, acc2[km][0], 0, 0, 0);
            #pragma unroll
            for (int km = 0; km < 4; ++km)
                acc2[km][0] = __builtin_amdgcn_mfma_f32_16x16x32_f16(fah[km], wl, acc2[km][0], 0, 0, 0);
            #pragma unroll
            for (int km = 0; km < 4; ++km)
                acc2[km][0] = __builtin_amdgcn_mfma_f32_16x16x32_f16(fal[km], wh, acc2[km][0], 0, 0, 0);
        }
        // ns = 1,2 (pure delta cols): 2-pass (w fp16 single, feat hi+lo)
        #pragma unroll
        for (int ns = 1; ns < 3; ++ns) {
            int eo = (ns * 16 + lr) * 512 + kg;
            fp16x8 wh = *(const fp16x8*)&bt2_hi[eo];
            #pragma unroll
            for (int km = 0; km < 4; ++km)
                acc2[km][ns] = __builtin_amdgcn_mfma_f32_16x16x32_f16(fah[km], wh, acc2[km][ns], 0, 0, 0);
            #pragma unroll
            for (int km = 0; km < 4; ++km)
                acc2[km][ns] = __builtin_amdgcn_mfma_f32_16x16x32_f16(fal[km], wh, acc2[km][ns], 0, 0, 0);
        }
    }

    // ---- deterministic staged cross-wave k-reduction (fixed FP order ->
    //      bitwise-identical output every launch) ----
    for (int w = 0; w < 4; ++w) {
        if (wave == w) {
            #pragma unroll
            for (int km = 0; km < 4; ++km)
                #pragma unroll
                for (int ns = 0; ns < 3; ++ns)
                    #pragma unroll
                    for (int r = 0; r < 4; ++r) {
                        int row = km * 16 + q * 4 + r;
                        int col = ns * 16 + lr;
                        float v = acc2[km][ns][r];
                        if (w == 0) zbuf[row * 48 + col] = v;
                        else        zbuf[row * 48 + col] += v;
                    }
        }
        __syncthreads();   // stage w complete before stage w+1 / epilogue
    }

    // ---- epilogue: sigmoid, threshold mask, store ----
    for (int i = tid; i < 64 * 45; i += 256) {
        int m = i / 45;
        int o = i - m * 45;
        float z = zbuf[m * 48 + o];
        float v;
        if (o < 9) {
            v = 1.f / (1.f + expf(-(z + b_cls[o])));
        } else {
            int d = o - 9;
            int a = d >> 2;
            float s = 1.f / (1.f + expf(-(zbuf[m * 48 + a] + b_cls[a])));
            v = (s > 0.7f) ? (z + b_reg[d]) : 0.f;
        }
        int mh = m >> 5, mw = m & 31;
        out[(((b * 256 + h0 + mh) * 256) + w0 + mw) * 45 + o] = v;
    }
}

// ---------------------------------------------------------------------------
extern "C" void kernel_launch(void* const* d_in, const int* in_sizes, int n_in,
                              void* d_out, int out_size, void* d_ws, size_t ws_size,
                              hipStream_t stream)
{
    const float* x      = (const float*)d_in[0];
    const float* w_base = (const float*)d_in[1];
    const float* b_base = (const float*)d_in[2];
    const float* w_cls  = (const float*)d_in[3];
    const float* b_cls  = (const float*)d_in[4];
    const float* w_reg  = (const float*)d_in[5];
    const float* b_reg  = (const float*)d_in[6];
    float* out = (float*)d_out;

    _Float16* btI    = (_Float16*)d_ws;
    _Float16* bt2_hi = btI + BT_ELEMS;
    _Float16* bt2_lo = bt2_hi + BT2_ELEMS;

    rpn_prep<<<(BT_ELEMS + BT2_ELEMS + 255) / 256, 256, 0, stream>>>(
        w_base, w_cls, w_reg, btI, bt2_hi, bt2_lo);
    rpn_main<<<4096, 256, 0, stream>>>(
        x, b_base, b_cls, b_reg, btI, bt2_hi, bt2_lo, out);
}